// Round 15
// baseline (774.483 us; speedup 1.0000x reference)
//
#include <hip/hip_runtime.h>
#include <hip/hip_bf16.h>

#define M_BATCH 65536
#define K_IN    1024
#define N_OUT   256
#define TAU     0.0625f

// d_ws layout (shorts): xhi [65536][1024], xlo [65536][1024], wt [256][1024]
#define XLO_SOFF 67108864ULL
#define WT_SOFF  134217728ULL
#define WS_NEED  268959744ULL   // bytes

typedef __attribute__((ext_vector_type(8))) short short8;
typedef __attribute__((ext_vector_type(4))) short short4v;
typedef __attribute__((ext_vector_type(4))) float f32x4;

__device__ inline short f2bf(float f) {
    __hip_bfloat16 h = __float2bfloat16(f);
    return __builtin_bit_cast(short, h);
}
__device__ inline float bf2f(short s) {
    unsigned u = ((unsigned)(unsigned short)s) << 16;
    return __builtin_bit_cast(float, u);
}

// ---- x -> bf16 hi/lo, elementwise layout (pure streaming) ----
__global__ __launch_bounds__(512) void presplit(const float* __restrict__ x,
                                                short* __restrict__ xhi,
                                                short* __restrict__ xlo) {
    const int stride = gridDim.x * 512;
    for (int idx = blockIdx.x * 512 + threadIdx.x; idx < M_BATCH * (K_IN / 4); idx += stride) {
        const float4 v = ((const float4*)x)[idx];
        short4v h, l;
        h.x = f2bf(v.x); l.x = f2bf(v.x - bf2f(h.x));
        h.y = f2bf(v.y); l.y = f2bf(v.y - bf2f(h.y));
        h.z = f2bf(v.z); l.z = f2bf(v.z - bf2f(h.z));
        h.w = f2bf(v.w); l.w = f2bf(v.w - bf2f(h.w));
        ((short4v*)xhi)[idx] = h;
        ((short4v*)xlo)[idx] = l;
    }
}

// ---- W -> bf16 (exact: ternary), elementwise layout ----
__global__ __launch_bounds__(512) void wconv(const float* __restrict__ w,
                                             short* __restrict__ wt) {
    const int idx = blockIdx.x * 512 + threadIdx.x;    // 65536 float4 total
    const float4 v = ((const float4*)w)[idx];
    short4v h;
    h.x = f2bf(v.x); h.y = f2bf(v.y); h.z = f2bf(v.z); h.w = f2bf(v.w);
    ((short4v*)wt)[idx] = h;
}

// ---- main: barrier-free per-wave MFMA GEMM.
// Each wave owns a 16-row x 256-col output strip. A (hi/lo bf16) and B (bf16
// W) fragments are loaded global->VGPR directly (A coalesced 16 lines/inst
// from HBM; B streamed from L2 - W is 0.5MB, L2-resident). No LDS, no
// __syncthreads: 4096 independent waves (16/CU) hide latency by TLP.
// Fragment mapping (r10..r14-verified): lane=(l4,l15); A row=l15, k=l4*8;
// B row(n)=l15, k=l4*8; C: m=l4*4+reg, n=l15.
// Band cells |t+0.5| < TAU -> C3-exact recompute (r8-verified ordering:
// kc=512 panels, one sequential f32 chain per panel, cs = p0 + p1).
__global__ __launch_bounds__(256) void binlin_wv(const float* __restrict__ x,
                                                 const float* __restrict__ wf,
                                                 const short* __restrict__ xhi,
                                                 const short* __restrict__ xlo,
                                                 const short* __restrict__ wt,
                                                 const float* __restrict__ bias,
                                                 const float* __restrict__ sign,
                                                 float* __restrict__ out) {
    const int lane = threadIdx.x & 63;
    const int wix  = blockIdx.x * 4 + (threadIdx.x >> 6);   // 0..4095
    const int l15  = lane & 15;
    const int l4   = lane >> 4;
    const int m0   = wix * 16;

    const short* pa_h = xhi + (size_t)(m0 + l15) * K_IN + l4 * 8;
    const short* pa_l = xlo + (size_t)(m0 + l15) * K_IN + l4 * 8;
    const short* pb   = wt  + (size_t)l15 * K_IN + l4 * 8;

    f32x4 acc[16];
#pragma unroll
    for (int g = 0; g < 16; ++g) acc[g] = (f32x4){0.f, 0.f, 0.f, 0.f};

    for (int kt = 0; kt < 32; ++kt) {
        const short8 Ah = *(const short8*)(pa_h + kt * 32);
        const short8 Al = *(const short8*)(pa_l + kt * 32);
#pragma unroll
        for (int g = 0; g < 16; g += 4) {
            const short8 B0 = *(const short8*)(pb + (size_t)(g + 0) * 16 * K_IN + kt * 32);
            const short8 B1 = *(const short8*)(pb + (size_t)(g + 1) * 16 * K_IN + kt * 32);
            const short8 B2 = *(const short8*)(pb + (size_t)(g + 2) * 16 * K_IN + kt * 32);
            const short8 B3 = *(const short8*)(pb + (size_t)(g + 3) * 16 * K_IN + kt * 32);
            acc[g + 0] = __builtin_amdgcn_mfma_f32_16x16x32_bf16(Ah, B0, acc[g + 0], 0, 0, 0);
            acc[g + 0] = __builtin_amdgcn_mfma_f32_16x16x32_bf16(Al, B0, acc[g + 0], 0, 0, 0);
            acc[g + 1] = __builtin_amdgcn_mfma_f32_16x16x32_bf16(Ah, B1, acc[g + 1], 0, 0, 0);
            acc[g + 1] = __builtin_amdgcn_mfma_f32_16x16x32_bf16(Al, B1, acc[g + 1], 0, 0, 0);
            acc[g + 2] = __builtin_amdgcn_mfma_f32_16x16x32_bf16(Ah, B2, acc[g + 2], 0, 0, 0);
            acc[g + 2] = __builtin_amdgcn_mfma_f32_16x16x32_bf16(Al, B2, acc[g + 2], 0, 0, 0);
            acc[g + 3] = __builtin_amdgcn_mfma_f32_16x16x32_bf16(Ah, B3, acc[g + 3], 0, 0, 0);
            acc[g + 3] = __builtin_amdgcn_mfma_f32_16x16x32_bf16(Al, B3, acc[g + 3], 0, 0, 0);
        }
    }

    // ---- epilogue: decide (+ C3-exact band fixup), coalesced f32 stores
    // (per (g,j) store: lanes l15 cover 16 contiguous cols -> 4 lines/inst)
#pragma unroll
    for (int g = 0; g < 16; ++g) {
        const int n = g * 16 + l15;
        const float b = bias[n];
        const float s = sign[n];
#pragma unroll
        for (int j = 0; j < 4; ++j) {
            const int m = m0 + l4 * 4 + j;
            const float t = (acc[g][j] + b) * s;
            float d;
            if (fabsf(t + 0.5f) < TAU) {
                const float* xr_ = x  + (size_t)m * K_IN;
                const float* wr_ = wf + (size_t)n * K_IN;
                float a0 = 0.f, a1 = 0.f;
                for (int k4 = 0; k4 < 128; ++k4) {
                    const float4 xv0 = *(const float4*)(xr_ + k4 * 4);
                    const float4 wv0 = *(const float4*)(wr_ + k4 * 4);
                    const float4 xv1 = *(const float4*)(xr_ + 512 + k4 * 4);
                    const float4 wv1 = *(const float4*)(wr_ + 512 + k4 * 4);
                    a0 = fmaf(xv0.x, wv0.x, a0); a1 = fmaf(xv1.x, wv1.x, a1);
                    a0 = fmaf(xv0.y, wv0.y, a0); a1 = fmaf(xv1.y, wv1.y, a1);
                    a0 = fmaf(xv0.z, wv0.z, a0); a1 = fmaf(xv1.z, wv1.z, a1);
                    a0 = fmaf(xv0.w, wv0.w, a0); a1 = fmaf(xv1.w, wv1.w, a1);
                }
                const float tt = ((a0 + a1) + b) * s;
                d = (tt >= -0.5f) ? 1.0f : 0.0f;
            } else {
                d = (t >= -0.5f) ? 1.0f : 0.0f;
            }
            out[(size_t)m * N_OUT + n] = d;
        }
    }
}

// ---- fallback (r9-proven): fp32 tiled GEMM + C3 band fixup ----
__global__ __launch_bounds__(256) void binlin_fast(const float* __restrict__ x,
                                                   const float* __restrict__ w,
                                                   const float* __restrict__ bias,
                                                   const float* __restrict__ sign,
                                                   float* __restrict__ out) {
    __shared__ float As[32][132];
    __shared__ float Bs[32][132];
    const int tid = threadIdx.x;
    const int tx  = tid & 15;
    const int ty  = tid >> 4;
    const int n0  = blockIdx.x * 128;
    const int m0  = blockIdx.y * 128;
    const int sr  = tid >> 3;
    const int sc  = (tid & 7) * 4;
    float acc[8][8];
#pragma unroll
    for (int i = 0; i < 8; ++i)
#pragma unroll
        for (int j = 0; j < 8; ++j) acc[i][j] = 0.f;
    for (int kt = 0; kt < K_IN; kt += 32) {
        __syncthreads();
#pragma unroll
        for (int q = 0; q < 4; ++q) {
            const int row = sr + q * 32;
            const float4 va = *(const float4*)(x + (size_t)(m0 + row) * K_IN + kt + sc);
            As[sc + 0][row] = va.x; As[sc + 1][row] = va.y;
            As[sc + 2][row] = va.z; As[sc + 3][row] = va.w;
            const float4 vb = *(const float4*)(w + (size_t)(n0 + row) * K_IN + kt + sc);
            Bs[sc + 0][row] = vb.x; Bs[sc + 1][row] = vb.y;
            Bs[sc + 2][row] = vb.z; Bs[sc + 3][row] = vb.w;
        }
        __syncthreads();
#pragma unroll
        for (int kk = 0; kk < 32; ++kk) {
            const float4 a0 = *(const float4*)&As[kk][ty * 8];
            const float4 a1 = *(const float4*)&As[kk][ty * 8 + 4];
            const float4 b0 = *(const float4*)&Bs[kk][tx * 8];
            const float4 b1 = *(const float4*)&Bs[kk][tx * 8 + 4];
            const float a[8] = {a0.x, a0.y, a0.z, a0.w, a1.x, a1.y, a1.z, a1.w};
            const float b[8] = {b0.x, b0.y, b0.z, b0.w, b1.x, b1.y, b1.z, b1.w};
#pragma unroll
            for (int i = 0; i < 8; ++i)
#pragma unroll
                for (int j = 0; j < 8; ++j)
                    acc[i][j] = fmaf(a[i], b[j], acc[i][j]);
        }
    }
    const int nb = n0 + tx * 8;
    float bv[8], sv[8];
#pragma unroll
    for (int j = 0; j < 8; ++j) { bv[j] = bias[nb + j]; sv[j] = sign[nb + j]; }
#pragma unroll
    for (int i = 0; i < 8; ++i) {
        const int m = m0 + ty * 8 + i;
        float o[8];
#pragma unroll
        for (int j = 0; j < 8; ++j) {
            const float t = (acc[i][j] + bv[j]) * sv[j];
            if (fabsf(t + 0.5f) < TAU) {
                const float* xr = x + (size_t)m * K_IN;
                const float* wr = w + (size_t)(nb + j) * K_IN;
                float cs = 0.f;
                for (int p = 0; p < 2; ++p) {
                    float a = 0.f;
                    const int kb = p * 512;
                    for (int k4 = 0; k4 < 128; ++k4) {
                        const float4 xv = *(const float4*)(xr + kb + k4 * 4);
                        const float4 wv = *(const float4*)(wr + kb + k4 * 4);
                        a = fmaf(xv.x, wv.x, a); a = fmaf(xv.y, wv.y, a);
                        a = fmaf(xv.z, wv.z, a); a = fmaf(xv.w, wv.w, a);
                    }
                    cs += a;
                }
                o[j] = (((cs + bv[j]) * sv[j]) >= -0.5f) ? 1.0f : 0.0f;
            } else {
                o[j] = (t >= -0.5f) ? 1.0f : 0.0f;
            }
        }
        float4* op = (float4*)(out + (size_t)m * N_OUT + nb);
        op[0] = make_float4(o[0], o[1], o[2], o[3]);
        op[1] = make_float4(o[4], o[5], o[6], o[7]);
    }
}

extern "C" void kernel_launch(void* const* d_in, const int* in_sizes, int n_in,
                              void* d_out, int out_size, void* d_ws, size_t ws_size,
                              hipStream_t stream) {
    const float* x    = (const float*)d_in[0];
    const float* w    = (const float*)d_in[1];
    const float* bias = (const float*)d_in[2];
    const float* sign = (const float*)d_in[3];

    if (n_in >= 4 && in_sizes[0] != M_BATCH * K_IN) {   // defensive no-op
        const float* small[2] = {nullptr, nullptr};
        int nsmall = 0;
        for (int i = 0; i < 4; ++i) {
            if (in_sizes[i] == M_BATCH * K_IN)      x = (const float*)d_in[i];
            else if (in_sizes[i] == N_OUT * K_IN)   w = (const float*)d_in[i];
            else if (nsmall < 2) small[nsmall++] = (const float*)d_in[i];
        }
        if (nsmall == 2) { bias = small[0]; sign = small[1]; }
    }

    float* out = (float*)d_out;

    if (ws_size >= WS_NEED) {
        short* xhi = (short*)d_ws;
        short* xlo = xhi + XLO_SOFF;
        short* wtp = xhi + WT_SOFF;
        presplit<<<2048, 512, 0, stream>>>(x, xhi, xlo);
        wconv<<<128, 512, 0, stream>>>(w, wtp);
        binlin_wv<<<M_BATCH / 64, 256, 0, stream>>>(x, w, xhi, xlo, wtp, bias, sign, out);
    } else {
        dim3 grid(N_OUT / 128, M_BATCH / 128);
        binlin_fast<<<grid, 256, 0, stream>>>(x, w, bias, sign, out);
    }
}

// Round 16
// 549.490 us; speedup vs baseline: 1.4095x; 1.4095x over previous
//
#include <hip/hip_runtime.h>
#include <hip/hip_bf16.h>

#define M_BATCH 65536
#define K_IN    1024
#define N_OUT   256
#define TAU     0.0625f

// d_ws layout (shorts): xhi [65536][1024], xlo [65536][1024], wt [256][1024]
#define XLO_SOFF 67108864ULL
#define WT_SOFF  134217728ULL
#define WS_NEED  268959744ULL   // bytes

typedef __attribute__((ext_vector_type(8))) short short8;
typedef __attribute__((ext_vector_type(4))) short short4v;
typedef __attribute__((ext_vector_type(4))) float f32x4;

__device__ inline short f2bf(float f) {
    __hip_bfloat16 h = __float2bfloat16(f);
    return __builtin_bit_cast(short, h);
}
__device__ inline float bf2f(short s) {
    unsigned u = ((unsigned)(unsigned short)s) << 16;
    return __builtin_bit_cast(float, u);
}
__device__ inline void gload16(const void* g, void* lds) {
    __builtin_amdgcn_global_load_lds(
        (const __attribute__((address_space(1))) unsigned int*)g,
        (__attribute__((address_space(3))) unsigned int*)lds, 16, 0, 0);
}

// Swizzled destination offset (shorts) for element k of row `row`:
// within each 64-k block, 16B cell c stored at c ^ (row & 7).
// Makes ds_read_b128 ~conflict-free with LINEAR LDS staging (rule #21).
__device__ inline size_t swz_dst(int row, int col4 /*float4 idx*/) {
    const int kb = col4 >> 4;          // 64-k block
    const int c  = (col4 >> 1) & 7;    // 16B cell within block
    const int h  = col4 & 1;           // half-cell
    return (size_t)row * K_IN + kb * 64 + ((c ^ (row & 7)) << 3) + h * 4;
}

// ---- x -> bf16 hi/lo, swizzled layout (pure streaming) ----
__global__ __launch_bounds__(512) void presplit(const float* __restrict__ x,
                                                short* __restrict__ xhi,
                                                short* __restrict__ xlo) {
    const int stride = gridDim.x * 512;
    for (int idx = blockIdx.x * 512 + threadIdx.x; idx < M_BATCH * (K_IN / 4); idx += stride) {
        const int row  = idx >> 8;
        const int col4 = idx & 255;
        const float4 v = ((const float4*)x)[idx];
        short4v h, l;
        h.x = f2bf(v.x); l.x = f2bf(v.x - bf2f(h.x));
        h.y = f2bf(v.y); l.y = f2bf(v.y - bf2f(h.y));
        h.z = f2bf(v.z); l.z = f2bf(v.z - bf2f(h.z));
        h.w = f2bf(v.w); l.w = f2bf(v.w - bf2f(h.w));
        const size_t dst = swz_dst(row, col4);
        *(short4v*)(xhi + dst) = h;
        *(short4v*)(xlo + dst) = l;
    }
}

// ---- W -> bf16 (exact: ternary), swizzled layout ----
__global__ __launch_bounds__(512) void wconv(const float* __restrict__ w,
                                             short* __restrict__ wt) {
    const int idx  = blockIdx.x * 512 + threadIdx.x;   // 65536 float4 total
    const int row  = idx >> 8;
    const int col4 = idx & 255;
    const float4 v = ((const float4*)w)[idx];
    short4v h;
    h.x = f2bf(v.x); h.y = f2bf(v.y); h.z = f2bf(v.z); h.w = f2bf(v.w);
    *(short4v*)(wt + swz_dst(row, col4)) = h;
}

// ---- main: m97-structure clone. 256 thr / 4 waves (2x2), 128x128 tile,
// BK=64, SINGLE-buffered LDS (48KB -> 3 blocks/CU), 2 barriers per K-step,
// gload_lds width-16 staging, XCD-chunked block swizzle.
// Band cells |t+0.5| < TAU -> C3-exact recompute (r8-verified ordering).
__global__ __launch_bounds__(256) void binlin_m97(const float* __restrict__ x,
                                                  const float* __restrict__ wf,
                                                  const short* __restrict__ xhi,
                                                  const short* __restrict__ xlo,
                                                  const short* __restrict__ wt,
                                                  const float* __restrict__ bias,
                                                  const float* __restrict__ sign,
                                                  float* __restrict__ out) {
    __shared__ __align__(16) short smem[24576];   // Ah 8K | Al 8K | B 8K shorts

    // bijective XCD-chunk swizzle: orig bid%8 = XCD; give each XCD a
    // contiguous logical range so (m, n=0/1) pairs co-reside -> x L2-dedup.
    const int bid     = blockIdx.x;                 // 0..1023
    const int logical = (bid & 7) * 128 + (bid >> 3);
    const int m0 = (logical >> 1) * 128;
    const int n0 = (logical & 1) * 128;

    const int tid  = threadIdx.x;
    const int lane = tid & 63;
    const int wid  = tid >> 6;       // 4 waves: 2(m) x 2(n)
    const int wm   = wid >> 1;
    const int wn   = wid & 1;
    const int l15  = lane & 15;
    const int l4   = lane >> 4;

    // staging: per wave, 4 insts x 8 rows x 128B per tile
    const int srow = wid * 32 + (lane >> 3);        // +inst*8
    const int scol = (lane & 7) * 8;                // shorts
    const size_t asrc = (size_t)(m0 + srow) * K_IN + scol;
    const size_t bsrc = (size_t)(n0 + srow) * K_IN + scol;

    f32x4 acc[4][4];
#pragma unroll
    for (int i = 0; i < 4; ++i)
#pragma unroll
        for (int j = 0; j < 4; ++j) acc[i][j] = (f32x4){0.f, 0.f, 0.f, 0.f};

    short* Ah = smem;
    short* Al = smem + 8192;
    short* Bs = smem + 16384;

    for (int kt = 0; kt < 16; ++kt) {
        __syncthreads();                            // prev compute done
#pragma unroll
        for (int q = 0; q < 4; ++q) {
            gload16(xhi + asrc + (size_t)q * 8 * K_IN + kt * 64, Ah + (wid * 32 + q * 8) * 64);
            gload16(xlo + asrc + (size_t)q * 8 * K_IN + kt * 64, Al + (wid * 32 + q * 8) * 64);
            gload16(wt  + bsrc + (size_t)q * 8 * K_IN + kt * 64, Bs + (wid * 32 + q * 8) * 64);
        }
        __syncthreads();                            // staging complete (vmcnt drains)

#pragma unroll
        for (int kk = 0; kk < 2; ++kk) {
            short8 bfr[4];
#pragma unroll
            for (int ni = 0; ni < 4; ++ni) {
                const int Rn = wn * 64 + ni * 16 + l15;
                bfr[ni] = *(const short8*)&Bs[Rn * 64 + (((kk * 4 + l4) ^ (Rn & 7)) << 3)];
            }
#pragma unroll
            for (int mi = 0; mi < 4; ++mi) {
                const int Rm  = wm * 64 + mi * 16 + l15;
                const int off = Rm * 64 + (((kk * 4 + l4) ^ (Rm & 7)) << 3);
                const short8 ahi = *(const short8*)&Ah[off];
                const short8 alo = *(const short8*)&Al[off];
#pragma unroll
                for (int ni = 0; ni < 4; ++ni) {
                    acc[mi][ni] = __builtin_amdgcn_mfma_f32_16x16x32_bf16(
                        ahi, bfr[ni], acc[mi][ni], 0, 0, 0);
                    acc[mi][ni] = __builtin_amdgcn_mfma_f32_16x16x32_bf16(
                        alo, bfr[ni], acc[mi][ni], 0, 0, 0);
                }
            }
        }
    }
    __syncthreads();

    // ---- epilogue: decide (+ C3-exact band fixup) -> u8 LDS -> coalesced out
    unsigned char* dec = (unsigned char*)smem;      // 16 KB overlay [128][128]
#pragma unroll
    for (int ni = 0; ni < 4; ++ni) {
        const int nl = wn * 64 + ni * 16 + l15;
        const int n  = n0 + nl;
        const float b = bias[n];
        const float s = sign[n];
#pragma unroll
        for (int mi = 0; mi < 4; ++mi) {
            const int ml = wm * 64 + mi * 16 + l4 * 4;
#pragma unroll
            for (int j = 0; j < 4; ++j) {
                const float t = (acc[mi][ni][j] + b) * s;
                unsigned char d;
                if (fabsf(t + 0.5f) < TAU) {
                    // C3-exact: kc=512 panels, one sequential f32 chain each
                    const float* xr_ = x  + (size_t)(m0 + ml + j) * K_IN;
                    const float* wr_ = wf + (size_t)n * K_IN;
                    float a0 = 0.f, a1 = 0.f;
                    for (int k4 = 0; k4 < 128; ++k4) {
                        const float4 xv0 = *(const float4*)(xr_ + k4 * 4);
                        const float4 wv0 = *(const float4*)(wr_ + k4 * 4);
                        const float4 xv1 = *(const float4*)(xr_ + 512 + k4 * 4);
                        const float4 wv1 = *(const float4*)(wr_ + 512 + k4 * 4);
                        a0 = fmaf(xv0.x, wv0.x, a0); a1 = fmaf(xv1.x, wv1.x, a1);
                        a0 = fmaf(xv0.y, wv0.y, a0); a1 = fmaf(xv1.y, wv1.y, a1);
                        a0 = fmaf(xv0.z, wv0.z, a0); a1 = fmaf(xv1.z, wv1.z, a1);
                        a0 = fmaf(xv0.w, wv0.w, a0); a1 = fmaf(xv1.w, wv1.w, a1);
                    }
                    const float tt = ((a0 + a1) + b) * s;
                    d = (tt >= -0.5f) ? 1 : 0;
                } else {
                    d = (t >= -0.5f) ? 1 : 0;
                }
                dec[(ml + j) * 128 + nl] = d;
            }
        }
    }
    __syncthreads();

#pragma unroll
    for (int it = 0; it < 16; ++it) {
        const int f   = it * 256 + tid;   // float4 index in 128x128 tile
        const int row = f >> 5;
        const int c4  = f & 31;
        const uchar4 dv = *(const uchar4*)&dec[row * 128 + c4 * 4];
        *(float4*)(out + (size_t)(m0 + row) * N_OUT + n0 + c4 * 4) =
            make_float4((float)dv.x, (float)dv.y, (float)dv.z, (float)dv.w);
    }
}

// ---- fallback (r9-proven): fp32 tiled GEMM + C3 band fixup ----
__global__ __launch_bounds__(256) void binlin_fast(const float* __restrict__ x,
                                                   const float* __restrict__ w,
                                                   const float* __restrict__ bias,
                                                   const float* __restrict__ sign,
                                                   float* __restrict__ out) {
    __shared__ float As[32][132];
    __shared__ float Bs2[32][132];
    const int tid = threadIdx.x;
    const int tx  = tid & 15;
    const int ty  = tid >> 4;
    const int n0  = blockIdx.x * 128;
    const int m0  = blockIdx.y * 128;
    const int sr  = tid >> 3;
    const int sc  = (tid & 7) * 4;
    float acc[8][8];
#pragma unroll
    for (int i = 0; i < 8; ++i)
#pragma unroll
        for (int j = 0; j < 8; ++j) acc[i][j] = 0.f;
    for (int kt = 0; kt < K_IN; kt += 32) {
        __syncthreads();
#pragma unroll
        for (int q = 0; q < 4; ++q) {
            const int row = sr + q * 32;
            const float4 va = *(const float4*)(x + (size_t)(m0 + row) * K_IN + kt + sc);
            As[sc + 0][row] = va.x; As[sc + 1][row] = va.y;
            As[sc + 2][row] = va.z; As[sc + 3][row] = va.w;
            const float4 vb = *(const float4*)(w + (size_t)(n0 + row) * K_IN + kt + sc);
            Bs2[sc + 0][row] = vb.x; Bs2[sc + 1][row] = vb.y;
            Bs2[sc + 2][row] = vb.z; Bs2[sc + 3][row] = vb.w;
        }
        __syncthreads();
#pragma unroll
        for (int kk = 0; kk < 32; ++kk) {
            const float4 a0 = *(const float4*)&As[kk][ty * 8];
            const float4 a1 = *(const float4*)&As[kk][ty * 8 + 4];
            const float4 b0 = *(const float4*)&Bs2[kk][tx * 8];
            const float4 b1 = *(const float4*)&Bs2[kk][tx * 8 + 4];
            const float a[8] = {a0.x, a0.y, a0.z, a0.w, a1.x, a1.y, a1.z, a1.w};
            const float b[8] = {b0.x, b0.y, b0.z, b0.w, b1.x, b1.y, b1.z, b1.w};
#pragma unroll
            for (int i = 0; i < 8; ++i)
#pragma unroll
                for (int j = 0; j < 8; ++j)
                    acc[i][j] = fmaf(a[i], b[j], acc[i][j]);
        }
    }
    const int nb = n0 + tx * 8;
    float bv[8], sv[8];
#pragma unroll
    for (int j = 0; j < 8; ++j) { bv[j] = bias[nb + j]; sv[j] = sign[nb + j]; }
#pragma unroll
    for (int i = 0; i < 8; ++i) {
        const int m = m0 + ty * 8 + i;
        float o[8];
#pragma unroll
        for (int j = 0; j < 8; ++j) {
            const float t = (acc[i][j] + bv[j]) * sv[j];
            if (fabsf(t + 0.5f) < TAU) {
                const float* xr = x + (size_t)m * K_IN;
                const float* wr = w + (size_t)(nb + j) * K_IN;
                float cs = 0.f;
                for (int p = 0; p < 2; ++p) {
                    float a = 0.f;
                    const int kb = p * 512;
                    for (int k4 = 0; k4 < 128; ++k4) {
                        const float4 xv = *(const float4*)(xr + kb + k4 * 4);
                        const float4 wv = *(const float4*)(wr + kb + k4 * 4);
                        a = fmaf(xv.x, wv.x, a); a = fmaf(xv.y, wv.y, a);
                        a = fmaf(xv.z, wv.z, a); a = fmaf(xv.w, wv.w, a);
                    }
                    cs += a;
                }
                o[j] = (((cs + bv[j]) * sv[j]) >= -0.5f) ? 1.0f : 0.0f;
            } else {
                o[j] = (t >= -0.5f) ? 1.0f : 0.0f;
            }
        }
        float4* op = (float4*)(out + (size_t)m * N_OUT + nb);
        op[0] = make_float4(o[0], o[1], o[2], o[3]);
        op[1] = make_float4(o[4], o[5], o[6], o[7]);
    }
}

extern "C" void kernel_launch(void* const* d_in, const int* in_sizes, int n_in,
                              void* d_out, int out_size, void* d_ws, size_t ws_size,
                              hipStream_t stream) {
    const float* x    = (const float*)d_in[0];
    const float* w    = (const float*)d_in[1];
    const float* bias = (const float*)d_in[2];
    const float* sign = (const float*)d_in[3];

    if (n_in >= 4 && in_sizes[0] != M_BATCH * K_IN) {   // defensive no-op
        const float* small[2] = {nullptr, nullptr};
        int nsmall = 0;
        for (int i = 0; i < 4; ++i) {
            if (in_sizes[i] == M_BATCH * K_IN)      x = (const float*)d_in[i];
            else if (in_sizes[i] == N_OUT * K_IN)   w = (const float*)d_in[i];
            else if (nsmall < 2) small[nsmall++] = (const float*)d_in[i];
        }
        if (nsmall == 2) { bias = small[0]; sign = small[1]; }
    }

    float* out = (float*)d_out;

    if (ws_size >= WS_NEED) {
        short* xhi = (short*)d_ws;
        short* xlo = xhi + XLO_SOFF;
        short* wtp = xhi + WT_SOFF;
        presplit<<<2048, 512, 0, stream>>>(x, xhi, xlo);
        wconv<<<128, 512, 0, stream>>>(w, wtp);
        binlin_m97<<<1024, 256, 0, stream>>>(x, w, xhi, xlo, wtp, bias, sign, out);
    } else {
        dim3 grid(N_OUT / 128, M_BATCH / 128);
        binlin_fast<<<grid, 256, 0, stream>>>(x, w, bias, sign, out);
    }
}

// Round 17
// 453.803 us; speedup vs baseline: 1.7066x; 1.2109x over previous
//
#include <hip/hip_runtime.h>
#include <hip/hip_bf16.h>

#define M_BATCH 65536
#define K_IN    1024
#define N_OUT   256
#define TAU     0.015f

// d_ws layout (shorts): xhi [65536][1024], xlo [65536][1024], wt [256][1024]
#define XLO_SOFF 67108864ULL
#define WT_SOFF  134217728ULL
#define WS_NEED  268959744ULL   // bytes

typedef __attribute__((ext_vector_type(8))) short short8;
typedef __attribute__((ext_vector_type(4))) short short4v;
typedef __attribute__((ext_vector_type(4))) float f32x4;

__device__ inline short f2bf(float f) {
    __hip_bfloat16 h = __float2bfloat16(f);
    return __builtin_bit_cast(short, h);
}
__device__ inline float bf2f(short s) {
    unsigned u = ((unsigned)(unsigned short)s) << 16;
    return __builtin_bit_cast(float, u);
}
__device__ inline void gload16(const void* g, void* lds) {
    __builtin_amdgcn_global_load_lds(
        (const __attribute__((address_space(1))) unsigned int*)g,
        (__attribute__((address_space(3))) unsigned int*)lds, 16, 0, 0);
}

// Swizzled destination offset (shorts) for element k of row `row`:
// within each 64-k block, 16B cell c stored at c ^ (row & 7) (rule #21).
__device__ inline size_t swz_dst(int row, int col4 /*float4 idx*/) {
    const int kb = col4 >> 4;
    const int c  = (col4 >> 1) & 7;
    const int h  = col4 & 1;
    return (size_t)row * K_IN + kb * 64 + ((c ^ (row & 7)) << 3) + h * 4;
}

// ---- x -> bf16 hi/lo, swizzled layout (pure streaming) ----
__global__ __launch_bounds__(512) void presplit(const float* __restrict__ x,
                                                short* __restrict__ xhi,
                                                short* __restrict__ xlo) {
    const int stride = gridDim.x * 512;
    for (int idx = blockIdx.x * 512 + threadIdx.x; idx < M_BATCH * (K_IN / 4); idx += stride) {
        const int row  = idx >> 8;
        const int col4 = idx & 255;
        const float4 v = ((const float4*)x)[idx];
        short4v h, l;
        h.x = f2bf(v.x); l.x = f2bf(v.x - bf2f(h.x));
        h.y = f2bf(v.y); l.y = f2bf(v.y - bf2f(h.y));
        h.z = f2bf(v.z); l.z = f2bf(v.z - bf2f(h.z));
        h.w = f2bf(v.w); l.w = f2bf(v.w - bf2f(h.w));
        const size_t dst = swz_dst(row, col4);
        *(short4v*)(xhi + dst) = h;
        *(short4v*)(xlo + dst) = l;
    }
}

// ---- W -> bf16 (exact: ternary), swizzled layout ----
__global__ __launch_bounds__(512) void wconv(const float* __restrict__ w,
                                             short* __restrict__ wt) {
    const int idx  = blockIdx.x * 512 + threadIdx.x;   // 65536 float4 total
    const int row  = idx >> 8;
    const int col4 = idx & 255;
    const float4 v = ((const float4*)w)[idx];
    short4v h;
    h.x = f2bf(v.x); h.y = f2bf(v.y); h.z = f2bf(v.z); h.w = f2bf(v.w);
    *(short4v*)(wt + swz_dst(row, col4)) = h;
}

// ---- main: m97-structure MFMA GEMM (r16) + CHEAP fixup:
// TAU 0.0625->0.015 (4.2x fewer band cells; spread RMS ~1e-4, pathological
// hard bound <9e-3 < TAU) and software-pipelined fixup loads (1-ahead,
// wrapped index so always in-bounds, decoupled from the FMA chain).
__global__ __launch_bounds__(256) void binlin_m97(const float* __restrict__ x,
                                                  const float* __restrict__ wf,
                                                  const short* __restrict__ xhi,
                                                  const short* __restrict__ xlo,
                                                  const short* __restrict__ wt,
                                                  const float* __restrict__ bias,
                                                  const float* __restrict__ sign,
                                                  float* __restrict__ out) {
    __shared__ __align__(16) short smem[24576];   // Ah 8K | Al 8K | B 8K shorts

    const int bid     = blockIdx.x;                 // 0..1023
    const int logical = (bid & 7) * 128 + (bid >> 3);
    const int m0 = (logical >> 1) * 128;
    const int n0 = (logical & 1) * 128;

    const int tid  = threadIdx.x;
    const int lane = tid & 63;
    const int wid  = tid >> 6;       // 4 waves: 2(m) x 2(n)
    const int wm   = wid >> 1;
    const int wn   = wid & 1;
    const int l15  = lane & 15;
    const int l4   = lane >> 4;

    const int srow = wid * 32 + (lane >> 3);
    const int scol = (lane & 7) * 8;
    const size_t asrc = (size_t)(m0 + srow) * K_IN + scol;
    const size_t bsrc = (size_t)(n0 + srow) * K_IN + scol;

    f32x4 acc[4][4];
#pragma unroll
    for (int i = 0; i < 4; ++i)
#pragma unroll
        for (int j = 0; j < 4; ++j) acc[i][j] = (f32x4){0.f, 0.f, 0.f, 0.f};

    short* Ah = smem;
    short* Al = smem + 8192;
    short* Bs = smem + 16384;

    for (int kt = 0; kt < 16; ++kt) {
        __syncthreads();
#pragma unroll
        for (int q = 0; q < 4; ++q) {
            gload16(xhi + asrc + (size_t)q * 8 * K_IN + kt * 64, Ah + (wid * 32 + q * 8) * 64);
            gload16(xlo + asrc + (size_t)q * 8 * K_IN + kt * 64, Al + (wid * 32 + q * 8) * 64);
            gload16(wt  + bsrc + (size_t)q * 8 * K_IN + kt * 64, Bs + (wid * 32 + q * 8) * 64);
        }
        __syncthreads();

#pragma unroll
        for (int kk = 0; kk < 2; ++kk) {
            short8 bfr[4];
#pragma unroll
            for (int ni = 0; ni < 4; ++ni) {
                const int Rn = wn * 64 + ni * 16 + l15;
                bfr[ni] = *(const short8*)&Bs[Rn * 64 + (((kk * 4 + l4) ^ (Rn & 7)) << 3)];
            }
#pragma unroll
            for (int mi = 0; mi < 4; ++mi) {
                const int Rm  = wm * 64 + mi * 16 + l15;
                const int off = Rm * 64 + (((kk * 4 + l4) ^ (Rm & 7)) << 3);
                const short8 ahi = *(const short8*)&Ah[off];
                const short8 alo = *(const short8*)&Al[off];
#pragma unroll
                for (int ni = 0; ni < 4; ++ni) {
                    acc[mi][ni] = __builtin_amdgcn_mfma_f32_16x16x32_bf16(
                        ahi, bfr[ni], acc[mi][ni], 0, 0, 0);
                    acc[mi][ni] = __builtin_amdgcn_mfma_f32_16x16x32_bf16(
                        alo, bfr[ni], acc[mi][ni], 0, 0, 0);
                }
            }
        }
    }
    __syncthreads();

    // ---- epilogue: decide (+ C3-exact band fixup) -> u8 LDS -> coalesced out
    unsigned char* dec = (unsigned char*)smem;      // 16 KB overlay [128][128]
#pragma unroll
    for (int ni = 0; ni < 4; ++ni) {
        const int nl = wn * 64 + ni * 16 + l15;
        const int n  = n0 + nl;
        const float b = bias[n];
        const float s = sign[n];
#pragma unroll
        for (int mi = 0; mi < 4; ++mi) {
            const int ml = wm * 64 + mi * 16 + l4 * 4;
#pragma unroll
            for (int j = 0; j < 4; ++j) {
                const float t = (acc[mi][ni][j] + b) * s;
                unsigned char d;
                if (fabsf(t + 0.5f) < TAU) {
                    // C3-exact: kc=512 panels, one sequential f32 chain each.
                    // Loads software-pipelined 1-ahead (wrapped index:
                    // always in-bounds) so they decouple from the FMA chain.
                    const float* xr_ = x  + (size_t)(m0 + ml + j) * K_IN;
                    const float* wr_ = wf + (size_t)n * K_IN;
                    float a0 = 0.f, a1 = 0.f;
                    float4 xc0 = *(const float4*)(xr_);
                    float4 wc0 = *(const float4*)(wr_);
                    float4 xc1 = *(const float4*)(xr_ + 512);
                    float4 wc1 = *(const float4*)(wr_ + 512);
                    for (int k4 = 0; k4 < 128; ++k4) {
                        const int kn = (k4 + 1) & 127;
                        const float4 nx0 = *(const float4*)(xr_ + kn * 4);
                        const float4 nw0 = *(const float4*)(wr_ + kn * 4);
                        const float4 nx1 = *(const float4*)(xr_ + 512 + kn * 4);
                        const float4 nw1 = *(const float4*)(wr_ + 512 + kn * 4);
                        a0 = fmaf(xc0.x, wc0.x, a0); a1 = fmaf(xc1.x, wc1.x, a1);
                        a0 = fmaf(xc0.y, wc0.y, a0); a1 = fmaf(xc1.y, wc1.y, a1);
                        a0 = fmaf(xc0.z, wc0.z, a0); a1 = fmaf(xc1.z, wc1.z, a1);
                        a0 = fmaf(xc0.w, wc0.w, a0); a1 = fmaf(xc1.w, wc1.w, a1);
                        xc0 = nx0; wc0 = nw0; xc1 = nx1; wc1 = nw1;
                    }
                    const float tt = ((a0 + a1) + b) * s;
                    d = (tt >= -0.5f) ? 1 : 0;
                } else {
                    d = (t >= -0.5f) ? 1 : 0;
                }
                dec[(ml + j) * 128 + nl] = d;
            }
        }
    }
    __syncthreads();

#pragma unroll
    for (int it = 0; it < 16; ++it) {
        const int f   = it * 256 + tid;   // float4 index in 128x128 tile
        const int row = f >> 5;
        const int c4  = f & 31;
        const uchar4 dv = *(const uchar4*)&dec[row * 128 + c4 * 4];
        *(float4*)(out + (size_t)(m0 + row) * N_OUT + n0 + c4 * 4) =
            make_float4((float)dv.x, (float)dv.y, (float)dv.z, (float)dv.w);
    }
}

// ---- fallback (r9-proven): fp32 tiled GEMM + C3 band fixup ----
__global__ __launch_bounds__(256) void binlin_fast(const float* __restrict__ x,
                                                   const float* __restrict__ w,
                                                   const float* __restrict__ bias,
                                                   const float* __restrict__ sign,
                                                   float* __restrict__ out) {
    __shared__ float As[32][132];
    __shared__ float Bs2[32][132];
    const int tid = threadIdx.x;
    const int tx  = tid & 15;
    const int ty  = tid >> 4;
    const int n0  = blockIdx.x * 128;
    const int m0  = blockIdx.y * 128;
    const int sr  = tid >> 3;
    const int sc  = (tid & 7) * 4;
    float acc[8][8];
#pragma unroll
    for (int i = 0; i < 8; ++i)
#pragma unroll
        for (int j = 0; j < 8; ++j) acc[i][j] = 0.f;
    for (int kt = 0; kt < K_IN; kt += 32) {
        __syncthreads();
#pragma unroll
        for (int q = 0; q < 4; ++q) {
            const int row = sr + q * 32;
            const float4 va = *(const float4*)(x + (size_t)(m0 + row) * K_IN + kt + sc);
            As[sc + 0][row] = va.x; As[sc + 1][row] = va.y;
            As[sc + 2][row] = va.z; As[sc + 3][row] = va.w;
            const float4 vb = *(const float4*)(w + (size_t)(n0 + row) * K_IN + kt + sc);
            Bs2[sc + 0][row] = vb.x; Bs2[sc + 1][row] = vb.y;
            Bs2[sc + 2][row] = vb.z; Bs2[sc + 3][row] = vb.w;
        }
        __syncthreads();
#pragma unroll
        for (int kk = 0; kk < 32; ++kk) {
            const float4 a0 = *(const float4*)&As[kk][ty * 8];
            const float4 a1 = *(const float4*)&As[kk][ty * 8 + 4];
            const float4 b0 = *(const float4*)&Bs2[kk][tx * 8];
            const float4 b1 = *(const float4*)&Bs2[kk][tx * 8 + 4];
            const float a[8] = {a0.x, a0.y, a0.z, a0.w, a1.x, a1.y, a1.z, a1.w};
            const float b[8] = {b0.x, b0.y, b0.z, b0.w, b1.x, b1.y, b1.z, b1.w};
#pragma unroll
            for (int i = 0; i < 8; ++i)
#pragma unroll
                for (int j = 0; j < 8; ++j)
                    acc[i][j] = fmaf(a[i], b[j], acc[i][j]);
        }
    }
    const int nb = n0 + tx * 8;
    float bv[8], sv[8];
#pragma unroll
    for (int j = 0; j < 8; ++j) { bv[j] = bias[nb + j]; sv[j] = sign[nb + j]; }
#pragma unroll
    for (int i = 0; i < 8; ++i) {
        const int m = m0 + ty * 8 + i;
        float o[8];
#pragma unroll
        for (int j = 0; j < 8; ++j) {
            const float t = (acc[i][j] + bv[j]) * sv[j];
            if (fabsf(t + 0.5f) < TAU) {
                const float* xr = x + (size_t)m * K_IN;
                const float* wr = w + (size_t)(nb + j) * K_IN;
                float cs = 0.f;
                for (int p = 0; p < 2; ++p) {
                    float a = 0.f;
                    const int kb = p * 512;
                    for (int k4 = 0; k4 < 128; ++k4) {
                        const float4 xv = *(const float4*)(xr + kb + k4 * 4);
                        const float4 wv = *(const float4*)(wr + kb + k4 * 4);
                        a = fmaf(xv.x, wv.x, a); a = fmaf(xv.y, wv.y, a);
                        a = fmaf(xv.z, wv.z, a); a = fmaf(xv.w, wv.w, a);
                    }
                    cs += a;
                }
                o[j] = (((cs + bv[j]) * sv[j]) >= -0.5f) ? 1.0f : 0.0f;
            } else {
                o[j] = (t >= -0.5f) ? 1.0f : 0.0f;
            }
        }
        float4* op = (float4*)(out + (size_t)m * N_OUT + nb);
        op[0] = make_float4(o[0], o[1], o[2], o[3]);
        op[1] = make_float4(o[4], o[5], o[6], o[7]);
    }
}

extern "C" void kernel_launch(void* const* d_in, const int* in_sizes, int n_in,
                              void* d_out, int out_size, void* d_ws, size_t ws_size,
                              hipStream_t stream) {
    const float* x    = (const float*)d_in[0];
    const float* w    = (const float*)d_in[1];
    const float* bias = (const float*)d_in[2];
    const float* sign = (const float*)d_in[3];

    if (n_in >= 4 && in_sizes[0] != M_BATCH * K_IN) {   // defensive no-op
        const float* small[2] = {nullptr, nullptr};
        int nsmall = 0;
        for (int i = 0; i < 4; ++i) {
            if (in_sizes[i] == M_BATCH * K_IN)      x = (const float*)d_in[i];
            else if (in_sizes[i] == N_OUT * K_IN)   w = (const float*)d_in[i];
            else if (nsmall < 2) small[nsmall++] = (const float*)d_in[i];
        }
        if (nsmall == 2) { bias = small[0]; sign = small[1]; }
    }

    float* out = (float*)d_out;

    if (ws_size >= WS_NEED) {
        short* xhi = (short*)d_ws;
        short* xlo = xhi + XLO_SOFF;
        short* wtp = xhi + WT_SOFF;
        presplit<<<2048, 512, 0, stream>>>(x, xhi, xlo);
        wconv<<<128, 512, 0, stream>>>(w, wtp);
        binlin_m97<<<1024, 256, 0, stream>>>(x, w, xhi, xlo, wtp, bias, sign, out);
    } else {
        dim3 grid(N_OUT / 128, M_BATCH / 128);
        binlin_fast<<<grid, 256, 0, stream>>>(x, w, bias, sign, out);
    }
}